// Round 2
// baseline (278.655 us; speedup 1.0000x reference)
//
#include <hip/hip_runtime.h>

// LinearAttention: N=8, L=S=4096, H=8, D=M=64, fp32.
// phase1 (8 s-splits): KVp[sp][nh][d][m] = sum_s phi(K)[s,d]*mask[s]*V[s,m]; Ksump likewise
// reduce: KVt = sum_sp KVp ; Ksum = sum_sp Ksump
// phase2: out[n,l,h,m] = (phi(Q)[l,:]·KVt[:,m]) / (phi(Q)[l,:]·Ksum + eps)

#define SLEN 4096
#define LLEN 4096
#define NHTOT 64      // N*H
#define HD   512      // H*D row stride in elements
#define NSPLIT 8
#define EPSF 1e-6f

__device__ __forceinline__ float phi(float x) {
    return x > 0.0f ? x + 1.0f : __expf(x);
}

__device__ __forceinline__ void fma4(float4& a, float s, const float4& b) {
    a.x = fmaf(s, b.x, a.x);
    a.y = fmaf(s, b.y, a.y);
    a.z = fmaf(s, b.z, a.z);
    a.w = fmaf(s, b.w, a.w);
}

// ---------------- Phase 1: per-split KV partials, barrier-free K-loop ----------------
// grid (NSPLIT, 64), block 256 = 4 waves. Each wave: 128 s-rows in 8 tiles of 16,
// staged into a PRIVATE per-wave LDS slice (no __syncthreads in the loop).
__global__ __launch_bounds__(256)
void la_phase1(const float* __restrict__ Kg, const float* __restrict__ Vg,
               const float* __restrict__ maskg,
               float* __restrict__ KVp, float* __restrict__ Ksump) {
    __shared__ float lds[8448];   // 4 waves x (Kbuf 16x68 + Vbuf 16x64) = 4*2112 floats

    const int tid  = threadIdx.x;
    const int w    = tid >> 6;
    const int lane = tid & 63;
    const int nh   = blockIdx.y;
    const int n    = nh >> 3;
    const int h    = nh & 7;
    const int sp   = blockIdx.x;

    // staging role: r = row-in-quad, c4 = 16B column chunk (fixed across j => ksp is one float4)
    const int r  = lane >> 4;        // 0..3
    const int c4 = lane & 15;        // 0..15
    // compute role: 8x8 output tile
    const int d0 = (lane & 7) * 8;
    const int m0 = (lane >> 3) * 8;

    float* kb = lds + w * 2112;      // [16][68] phi(K)*mask
    float* vb = kb + 1088;           // [16][64] V

    const size_t base = (size_t)n * SLEN * HD + (size_t)h * 64;
    const float* mrow = maskg + (size_t)n * SLEN;
    const int swave = sp * 512 + w * 128;

    float4 acc[8][2];
    #pragma unroll
    for (int i = 0; i < 8; ++i) {
        acc[i][0] = make_float4(0.f, 0.f, 0.f, 0.f);
        acc[i][1] = make_float4(0.f, 0.f, 0.f, 0.f);
    }
    float4 ksp = make_float4(0.f, 0.f, 0.f, 0.f);

    float4 kr[4], vr[4];
    float  mr[4];
    // prologue: load tile 0
    #pragma unroll
    for (int j = 0; j < 4; ++j) {
        const int s = swave + r + 4 * j;
        const size_t g = base + (size_t)s * HD + c4 * 4;
        kr[j] = *(const float4*)(Kg + g);
        vr[j] = *(const float4*)(Vg + g);
        mr[j] = mrow[s];
    }

    #pragma unroll 1
    for (int t = 0; t < 8; ++t) {
        float4 kn[4], vn[4];
        float  mn[4];
        if (t < 7) {  // issue next tile's loads before touching this tile (prefetch)
            const int s0 = swave + (t + 1) * 16;
            #pragma unroll
            for (int j = 0; j < 4; ++j) {
                const int s = s0 + r + 4 * j;
                const size_t g = base + (size_t)s * HD + c4 * 4;
                kn[j] = *(const float4*)(Kg + g);
                vn[j] = *(const float4*)(Vg + g);
                mn[j] = mrow[s];
            }
        }
        // stage tile t (phi once per element)
        #pragma unroll
        for (int j = 0; j < 4; ++j) {
            float4 kf = kr[j];
            const float mm = mr[j];
            kf.x = phi(kf.x) * mm;
            kf.y = phi(kf.y) * mm;
            kf.z = phi(kf.z) * mm;
            kf.w = phi(kf.w) * mm;
            ksp.x += kf.x; ksp.y += kf.y; ksp.z += kf.z; ksp.w += kf.w;
            const int row = r + 4 * j;
            *(float4*)&kb[row * 68 + c4 * 4] = kf;
            *(float4*)&vb[row * 64 + c4 * 4] = vr[j];
        }
        // compute tile t (same-wave DS ordering guarantees writes land before reads)
        #pragma unroll
        for (int s = 0; s < 16; ++s) {
            const float4 ka  = *(const float4*)&kb[s * 68 + d0];
            const float4 kc  = *(const float4*)&kb[s * 68 + d0 + 4];
            const float4 va  = *(const float4*)&vb[s * 64 + m0];
            const float4 vc  = *(const float4*)&vb[s * 64 + m0 + 4];
            const float kk[8] = {ka.x, ka.y, ka.z, ka.w, kc.x, kc.y, kc.z, kc.w};
            #pragma unroll
            for (int di = 0; di < 8; ++di) {
                fma4(acc[di][0], kk[di], va);
                fma4(acc[di][1], kk[di], vc);
            }
        }
        if (t < 7) {
            #pragma unroll
            for (int j = 0; j < 4; ++j) { kr[j] = kn[j]; vr[j] = vn[j]; mr[j] = mn[j]; }
        }
    }

    // ---------------- epilogue: cross-wave tree reduce (3 barriers) ----------------
    __syncthreads();  // (1) all waves done with their buffers

    // Ksum: butterfly across the 4 r-groups (lanes xor 16,32 share c4)
    ksp.x += __shfl_xor(ksp.x, 16); ksp.y += __shfl_xor(ksp.y, 16);
    ksp.z += __shfl_xor(ksp.z, 16); ksp.w += __shfl_xor(ksp.w, 16);
    ksp.x += __shfl_xor(ksp.x, 32); ksp.y += __shfl_xor(ksp.y, 32);
    ksp.z += __shfl_xor(ksp.z, 32); ksp.w += __shfl_xor(ksp.w, 32);
    if (lane < 16) *(float4*)&lds[8192 + w * 64 + lane * 4] = ksp;   // KsB region

    float* Red0 = lds;          // [64][64]
    float* Red1 = lds + 4096;   // [64][64]
    if (w == 2) {
        #pragma unroll
        for (int di = 0; di < 8; ++di) {
            *(float4*)&Red0[(d0 + di) * 64 + m0]     = acc[di][0];
            *(float4*)&Red0[(d0 + di) * 64 + m0 + 4] = acc[di][1];
        }
    }
    if (w == 3) {
        #pragma unroll
        for (int di = 0; di < 8; ++di) {
            *(float4*)&Red1[(d0 + di) * 64 + m0]     = acc[di][0];
            *(float4*)&Red1[(d0 + di) * 64 + m0 + 4] = acc[di][1];
        }
    }
    __syncthreads();  // (2)
    if (w == 0) {
        #pragma unroll
        for (int di = 0; di < 8; ++di) {
            const float4 a = *(const float4*)&Red0[(d0 + di) * 64 + m0];
            const float4 b = *(const float4*)&Red0[(d0 + di) * 64 + m0 + 4];
            acc[di][0].x += a.x; acc[di][0].y += a.y; acc[di][0].z += a.z; acc[di][0].w += a.w;
            acc[di][1].x += b.x; acc[di][1].y += b.y; acc[di][1].z += b.z; acc[di][1].w += b.w;
        }
    }
    if (w == 1) {
        #pragma unroll
        for (int di = 0; di < 8; ++di) {
            const float4 a = *(const float4*)&Red1[(d0 + di) * 64 + m0];
            const float4 b = *(const float4*)&Red1[(d0 + di) * 64 + m0 + 4];
            acc[di][0].x += a.x; acc[di][0].y += a.y; acc[di][0].z += a.z; acc[di][0].w += a.w;
            acc[di][1].x += b.x; acc[di][1].y += b.y; acc[di][1].z += b.z; acc[di][1].w += b.w;
        }
    }
    if (tid < 16) {  // finalize Ksum partial for this block
        float4 s = make_float4(0.f, 0.f, 0.f, 0.f);
        #pragma unroll
        for (int ww = 0; ww < 4; ++ww) {
            const float4 v = *(const float4*)&lds[8192 + ww * 64 + tid * 4];
            s.x += v.x; s.y += v.y; s.z += v.z; s.w += v.w;
        }
        *(float4*)&Ksump[((size_t)sp * NHTOT + nh) * 64 + tid * 4] = s;
    }
    __syncthreads();  // (3)
    if (w == 1) {
        #pragma unroll
        for (int di = 0; di < 8; ++di) {
            *(float4*)&Red0[(d0 + di) * 64 + m0]     = acc[di][0];
            *(float4*)&Red0[(d0 + di) * 64 + m0 + 4] = acc[di][1];
        }
    }
    __syncthreads();  // (4)
    if (w == 0) {
        float* outp = KVp + ((size_t)sp * NHTOT + nh) * 4096;
        #pragma unroll
        for (int di = 0; di < 8; ++di) {
            const float4 a = *(const float4*)&Red0[(d0 + di) * 64 + m0];
            const float4 b = *(const float4*)&Red0[(d0 + di) * 64 + m0 + 4];
            float4 o0 = acc[di][0], o1 = acc[di][1];
            o0.x += a.x; o0.y += a.y; o0.z += a.z; o0.w += a.w;
            o1.x += b.x; o1.y += b.y; o1.z += b.z; o1.w += b.w;
            *(float4*)&outp[(d0 + di) * 64 + m0]     = o0;
            *(float4*)&outp[(d0 + di) * 64 + m0 + 4] = o1;
        }
    }
}

// ---------------- Reduce: sum the 8 split partials ----------------
// grid 64 (one per nh), block 256
__global__ __launch_bounds__(256)
void la_reduce(const float* __restrict__ KVp, const float* __restrict__ Ksump,
               float* __restrict__ KVt, float* __restrict__ Ksum) {
    const int nh  = blockIdx.x;
    const int tid = threadIdx.x;
    #pragma unroll
    for (int j = 0; j < 4; ++j) {
        const int f = (j * 256 + tid) * 4;
        float4 a = make_float4(0.f, 0.f, 0.f, 0.f);
        #pragma unroll
        for (int s = 0; s < NSPLIT; ++s) {
            const float4 v = *(const float4*)&KVp[((size_t)s * NHTOT + nh) * 4096 + f];
            a.x += v.x; a.y += v.y; a.z += v.z; a.w += v.w;
        }
        *(float4*)&KVt[(size_t)nh * 4096 + f] = a;
    }
    if (tid < 16) {
        float4 a = make_float4(0.f, 0.f, 0.f, 0.f);
        #pragma unroll
        for (int s = 0; s < NSPLIT; ++s) {
            const float4 v = *(const float4*)&Ksump[((size_t)s * NHTOT + nh) * 64 + tid * 4];
            a.x += v.x; a.y += v.y; a.z += v.z; a.w += v.w;
        }
        *(float4*)&Ksum[nh * 64 + tid * 4] = a;
    }
}

// ---------------- Phase 2: out = phi(Q) @ KVt, normalized ----------------
// grid (L/64, 64), block 256. Each thread: 1 l-row (in registers) x 16 m.
// LDS = KV tile + Ksum only (16.6 KB) -> high occupancy, 1 barrier.
__global__ __launch_bounds__(256)
void la_phase2(const float* __restrict__ Qg, const float* __restrict__ KVt,
               const float* __restrict__ Ksum, float* __restrict__ Og) {
    __shared__ float KVs[4096];
    __shared__ float KSs[64];

    const int tid  = threadIdx.x;
    const int nh   = blockIdx.y;
    const int n    = nh >> 3;
    const int h    = nh & 7;
    const int w    = tid >> 6;
    const int lane = tid & 63;
    const int ty   = lane >> 2;           // 16 rows per wave
    const int tx   = lane & 3;            // 4 m-groups of 16
    const int row  = blockIdx.x * 64 + w * 16 + ty;
    const int m0   = tx * 16;

    // stage KV + Ksum (coalesced, L2-hot)
    #pragma unroll
    for (int j = 0; j < 4; ++j) {
        const int f = (j * 256 + tid) * 4;
        *(float4*)&KVs[f] = *(const float4*)&KVt[(size_t)nh * 4096 + f];
    }
    if (tid < 16) *(float4*)&KSs[tid * 4] = *(const float4*)&Ksum[nh * 64 + tid * 4];

    // load this thread's Q row into registers (4-lane same-address dedup via L1), phi once
    const size_t qoff = ((size_t)(n * LLEN + row) * 8 + h) * 64;
    float4 q[16];
    #pragma unroll
    for (int j = 0; j < 16; ++j) q[j] = *(const float4*)&Qg[qoff + j * 4];
    #pragma unroll
    for (int j = 0; j < 16; ++j) {
        q[j].x = phi(q[j].x); q[j].y = phi(q[j].y);
        q[j].z = phi(q[j].z); q[j].w = phi(q[j].w);
    }
    __syncthreads();

    float4 a0 = make_float4(0.f, 0.f, 0.f, 0.f);
    float4 a1 = a0, a2 = a0, a3 = a0;
    float den = 0.f;

    #pragma unroll
    for (int j = 0; j < 16; ++j) {
        const float4 q4 = q[j];
        const float4 ks = *(const float4*)&KSs[j * 4];
        den = fmaf(q4.x, ks.x, den);
        den = fmaf(q4.y, ks.y, den);
        den = fmaf(q4.z, ks.z, den);
        den = fmaf(q4.w, ks.w, den);
        #pragma unroll
        for (int dk = 0; dk < 4; ++dk) {
            const int d = j * 4 + dk;
            const float qs = (&q4.x)[dk];
            const float4 kv0 = *(const float4*)&KVs[d * 64 + m0];
            const float4 kv1 = *(const float4*)&KVs[d * 64 + m0 + 4];
            const float4 kv2 = *(const float4*)&KVs[d * 64 + m0 + 8];
            const float4 kv3 = *(const float4*)&KVs[d * 64 + m0 + 12];
            fma4(a0, qs, kv0);
            fma4(a1, qs, kv1);
            fma4(a2, qs, kv2);
            fma4(a3, qs, kv3);
        }
    }

    const float z = 1.0f / (den + EPSF);
    a0.x *= z; a0.y *= z; a0.z *= z; a0.w *= z;
    a1.x *= z; a1.y *= z; a1.z *= z; a1.w *= z;
    a2.x *= z; a2.y *= z; a2.z *= z; a2.w *= z;
    a3.x *= z; a3.y *= z; a3.z *= z; a3.w *= z;
    float* op = Og + ((size_t)(n * LLEN + row) * 8 + h) * 64 + m0;
    *(float4*)&op[0]  = a0;
    *(float4*)&op[4]  = a1;
    *(float4*)&op[8]  = a2;
    *(float4*)&op[12] = a3;
}

extern "C" void kernel_launch(void* const* d_in, const int* in_sizes, int n_in,
                              void* d_out, int out_size, void* d_ws, size_t ws_size,
                              hipStream_t stream) {
    const float* Q    = (const float*)d_in[0];
    const float* K    = (const float*)d_in[1];
    const float* V    = (const float*)d_in[2];
    const float* mask = (const float*)d_in[3];
    float* out = (float*)d_out;

    float* KVp   = (float*)d_ws;                                  // [8][64][4096]
    float* Ksump = KVp + (size_t)NSPLIT * NHTOT * 4096;           // [8][64][64]
    float* KVt   = Ksump + (size_t)NSPLIT * NHTOT * 64;           // [64][4096]
    float* Ksum  = KVt + (size_t)NHTOT * 4096;                    // [64][64]
    // total ws use: ~9.6 MB; every element read is written first (no memset needed)

    dim3 g1(NSPLIT, NHTOT);
    la_phase1<<<g1, 256, 0, stream>>>(K, V, mask, KVp, Ksump);

    la_reduce<<<NHTOT, 256, 0, stream>>>(KVp, Ksump, KVt, Ksum);

    dim3 g2(LLEN / 64, NHTOT);
    la_phase2<<<g2, 256, 0, stream>>>(Q, KVt, Ksum, out);
}

// Round 3
// 255.148 us; speedup vs baseline: 1.0921x; 1.0921x over previous
//
#include <hip/hip_runtime.h>

// LinearAttention: N=8, L=S=4096, H=8, D=M=64, fp32.
// phase1 (16 s-splits): KVp[sp][nh][d][m] = sum_s phi(K)[s,d]*mask[s]*V[s,m]; Ksump likewise
// reduce: KVt = sum_sp KVp ; Ksum = sum_sp Ksump
// phase2: out[n,l,h,m] = (phi(Q)[l,:]·KVt[:,m]) / (phi(Q)[l,:]·Ksum + eps)

#define SLEN 4096
#define LLEN 4096
#define NHTOT 64      // N*H
#define HD   512      // H*D row stride in elements
#define NSPLIT 16
#define EPSF 1e-6f

__device__ __forceinline__ float phi(float x) {
    return x > 0.0f ? x + 1.0f : __expf(x);
}

__device__ __forceinline__ void fma4(float4& a, float s, const float4& b) {
    a.x = fmaf(s, b.x, a.x);
    a.y = fmaf(s, b.y, a.y);
    a.z = fmaf(s, b.z, a.z);
    a.w = fmaf(s, b.w, a.w);
}

// ---------------- Phase 1: per-split KV partials ----------------
// grid (NSPLIT, 64), block 256 = 4 waves. Block: 256 s-rows in 4 tiles of 64.
// Each wave owns a 32x32 (d,m) QUADRANT (acc = 16 VGPR/lane, no cross-wave reduce).
// Compute reads are 4-consecutive-float chunks -> 128 B contiguous/inst, conflict-free.
__global__ __launch_bounds__(256)
void la_phase1(const float* __restrict__ Kg, const float* __restrict__ Vg,
               const float* __restrict__ maskg,
               float* __restrict__ KVp, float* __restrict__ Ksump) {
    __shared__ float kb[64 * 68];    // phi(K)*mask, padded stride 68 (17.4 KB)
    __shared__ float vb[64 * 64];    // V (16 KB)
    __shared__ float ksb[16 * 64];   // ksum partials (4 KB)  -> total 37.9 KB, 4 blocks/CU

    const int tid  = threadIdx.x;
    const int w    = tid >> 6;
    const int lane = tid & 63;
    const int nh   = blockIdx.y;
    const int n    = nh >> 3;
    const int h    = nh & 7;
    const int sp   = blockIdx.x;

    // staging role: 16 rows x 16 chunks per issue
    const int sr = tid >> 4;          // 0..15
    const int c4 = (tid & 15) * 4;    // float column
    // compute role: wave quadrant + 4x4 per-lane tile (contiguous 4-float slices)
    const int wd = w & 1, wm = w >> 1;
    const int d0 = wd * 32 + (lane & 7) * 4;
    const int m0 = wm * 32 + (lane >> 3) * 4;

    const size_t base = (size_t)n * SLEN * HD + (size_t)h * 64;
    const float* mrow = maskg + (size_t)n * SLEN;
    const int sblock = sp * 256;

    float4 acc[4];
    #pragma unroll
    for (int i = 0; i < 4; ++i) acc[i] = make_float4(0.f, 0.f, 0.f, 0.f);
    float4 ksp = make_float4(0.f, 0.f, 0.f, 0.f);

    for (int t = 0; t < 4; ++t) {
        const int srow0 = sblock + t * 64;
        __syncthreads();   // previous tile's reads done before overwrite
        #pragma unroll
        for (int u = 0; u < 4; ++u) {
            const int row = sr + u * 16;
            const int s   = srow0 + row;
            const size_t g = base + (size_t)s * HD + c4;
            float4 kf = *(const float4*)(Kg + g);
            const float mm = mrow[s];
            kf.x = phi(kf.x) * mm;
            kf.y = phi(kf.y) * mm;
            kf.z = phi(kf.z) * mm;
            kf.w = phi(kf.w) * mm;
            ksp.x += kf.x; ksp.y += kf.y; ksp.z += kf.z; ksp.w += kf.w;
            *(float4*)&kb[row * 68 + c4] = kf;
            *(float4*)&vb[row * 64 + c4] = *(const float4*)(Vg + g);
        }
        __syncthreads();
        #pragma unroll 8
        for (int s = 0; s < 64; ++s) {
            const float4 k4 = *(const float4*)&kb[s * 68 + d0];
            const float4 v4 = *(const float4*)&vb[s * 64 + m0];
            fma4(acc[0], k4.x, v4);
            fma4(acc[1], k4.y, v4);
            fma4(acc[2], k4.z, v4);
            fma4(acc[3], k4.w, v4);
        }
    }

    // ---- store quadrant (each wave owns disjoint (d,m): no reduce needed) ----
    float* outp = KVp + ((size_t)sp * NHTOT + nh) * 4096;
    #pragma unroll
    for (int di = 0; di < 4; ++di)
        *(float4*)&outp[(d0 + di) * 64 + m0] = acc[di];

    // ---- Ksum block reduce ----
    *(float4*)&ksb[sr * 64 + c4] = ksp;
    __syncthreads();
    if (tid < 64) {
        float ssum = 0.f;
        #pragma unroll
        for (int r = 0; r < 16; ++r) ssum += ksb[r * 64 + tid];
        Ksump[((size_t)sp * NHTOT + nh) * 64 + tid] = ssum;
    }
}

// ---------------- Reduce: sum the 16 split partials ----------------
// grid 64 (one per nh), block 256
__global__ __launch_bounds__(256)
void la_reduce(const float* __restrict__ KVp, const float* __restrict__ Ksump,
               float* __restrict__ KVt, float* __restrict__ Ksum) {
    const int nh  = blockIdx.x;
    const int tid = threadIdx.x;
    #pragma unroll
    for (int j = 0; j < 4; ++j) {
        const int f = (j * 256 + tid) * 4;
        float4 a = make_float4(0.f, 0.f, 0.f, 0.f);
        #pragma unroll
        for (int s = 0; s < NSPLIT; ++s) {
            const float4 v = *(const float4*)&KVp[((size_t)s * NHTOT + nh) * 4096 + f];
            a.x += v.x; a.y += v.y; a.z += v.z; a.w += v.w;
        }
        *(float4*)&KVt[(size_t)nh * 4096 + f] = a;
    }
    if (tid < 64) {
        float a = 0.f;
        #pragma unroll
        for (int s = 0; s < NSPLIT; ++s)
            a += Ksump[((size_t)s * NHTOT + nh) * 64 + tid];
        Ksum[nh * 64 + tid] = a;
    }
}

// ---------------- Phase 2: out = phi(Q) @ KVt, normalized ----------------
// grid (L/128, 64), block 256 = 4 waves; 128 Q-rows staged in LDS (phi once).
// Thread: 8 rows (stride 4) x 4 consecutive m. Stores are fully dense 1 KB/inst.
__global__ __launch_bounds__(256)
void la_phase2(const float* __restrict__ Qg, const float* __restrict__ KVt,
               const float* __restrict__ Ksum, float* __restrict__ Og) {
    __shared__ float Qs[128 * 68];  // 34.8 KB
    __shared__ float KVs[64 * 64];  // 16.4 KB
    __shared__ float KSs[64];       // total 51.5 KB -> 3 blocks/CU, 12 waves/CU

    const int tid = threadIdx.x;
    const int nh  = blockIdx.y;
    const int n   = nh >> 3;
    const int h   = nh & 7;
    const int lbase = blockIdx.x * 128;

    // ---- stage KV + Ksum (L2-hot, coalesced) ----
    #pragma unroll
    for (int j = 0; j < 4; ++j) {
        const int f = (j * 256 + tid) * 4;
        *(float4*)&KVs[f] = *(const float4*)&KVt[(size_t)nh * 4096 + f];
    }
    if (tid < 16) *(float4*)&KSs[tid * 4] = *(const float4*)&Ksum[nh * 64 + tid * 4];

    // ---- stage phi(Q) ----
    const int sr = tid >> 4;          // 0..15
    const int c4 = (tid & 15) * 4;
    #pragma unroll
    for (int u = 0; u < 8; ++u) {
        const int row = sr + u * 16;
        float4 q = *(const float4*)&Qg[((size_t)(n * LLEN + lbase + row) * 8 + h) * 64 + c4];
        q.x = phi(q.x); q.y = phi(q.y); q.z = phi(q.z); q.w = phi(q.w);
        *(float4*)&Qs[row * 68 + c4] = q;
    }
    __syncthreads();

    const int w    = tid >> 6;        // wave -> 32-row band
    const int lane = tid & 63;
    const int ty   = lane >> 4;       // 0..3
    const int tx   = lane & 15;
    const int m0   = tx * 4;
    const int rb   = w * 32 + ty;     // rows rb + 4*i

    float4 acc[8];
    float  den[8];
    #pragma unroll
    for (int i = 0; i < 8; ++i) {
        acc[i] = make_float4(0.f, 0.f, 0.f, 0.f);
        den[i] = 0.f;
    }

    for (int d4 = 0; d4 < 16; ++d4) {
        const float4 ks = *(const float4*)&KSs[d4 * 4];
        float4 q4[8];
        #pragma unroll
        for (int i = 0; i < 8; ++i)
            q4[i] = *(const float4*)&Qs[(rb + 4 * i) * 68 + d4 * 4];
        #pragma unroll
        for (int i = 0; i < 8; ++i) {
            den[i] = fmaf(q4[i].x, ks.x, den[i]);
            den[i] = fmaf(q4[i].y, ks.y, den[i]);
            den[i] = fmaf(q4[i].z, ks.z, den[i]);
            den[i] = fmaf(q4[i].w, ks.w, den[i]);
        }
        #pragma unroll
        for (int dk = 0; dk < 4; ++dk) {
            const float4 kv = *(const float4*)&KVs[(d4 * 4 + dk) * 64 + m0];
            #pragma unroll
            for (int i = 0; i < 8; ++i)
                fma4(acc[i], (&q4[i].x)[dk], kv);
        }
    }

    // ---- normalize + store (lanes cover 4 rows x 256 B contiguous per inst) ----
    #pragma unroll
    for (int i = 0; i < 8; ++i) {
        const int l = lbase + rb + 4 * i;
        const float z = 1.0f / (den[i] + EPSF);
        float4 o = acc[i];
        o.x *= z; o.y *= z; o.z *= z; o.w *= z;
        *(float4*)&Og[((size_t)(n * LLEN + l) * 8 + h) * 64 + m0] = o;
    }
}

extern "C" void kernel_launch(void* const* d_in, const int* in_sizes, int n_in,
                              void* d_out, int out_size, void* d_ws, size_t ws_size,
                              hipStream_t stream) {
    const float* Q    = (const float*)d_in[0];
    const float* K    = (const float*)d_in[1];
    const float* V    = (const float*)d_in[2];
    const float* mask = (const float*)d_in[3];
    float* out = (float*)d_out;

    float* KVp   = (float*)d_ws;                                  // [16][64][4096] = 16 MB
    float* Ksump = KVp + (size_t)NSPLIT * NHTOT * 4096;           // [16][64][64]
    float* KVt   = Ksump + (size_t)NSPLIT * NHTOT * 64;           // [64][4096]
    float* Ksum  = KVt + (size_t)NHTOT * 4096;                    // [64][64]
    // every ws element read is written first (no memset needed)

    dim3 g1(NSPLIT, NHTOT);
    la_phase1<<<g1, 256, 0, stream>>>(K, V, mask, KVp, Ksump);

    la_reduce<<<NHTOT, 256, 0, stream>>>(KVp, Ksump, KVt, Ksum);

    dim3 g2(LLEN / 128, NHTOT);
    la_phase2<<<g2, 256, 0, stream>>>(Q, KVt, Ksum, out);
}